// Round 2
// baseline (497.678 us; speedup 1.0000x reference)
//
#include <hip/hip_runtime.h>

// L2_Self_Attn flattened pipeline for MI355X (gfx950).
// B=4, C=128, H=W=64, N=4096. All reshapes are flat-view reinterpretations.
// Attention branch is suppressed by gamma/bound ~6e-6 -> bf16 MFMA is safe.
//
// Pipeline:
//  prep : WqT, WvT, scale = gamma/bound (Frobenius norms + LambertW const)
//  k1a  : Q = conv1x1(x,Wq,bq) -> Qb bf16 [B][N][C]; biasg = s*||q_n||^2
//  k1b  : Vt bf16 [B][C][N] = transpose of x viewed (N,C)
//  k2   : flash attention, 4 waves = 2 key-split pairs + LDS merge,
//         logits = 2s*q.k - biasg[m]; XCD-swizzled 1-D grid (batch->XCD pair)
//  g1   : F1.Vc = Wq @ F0.Vc + bq      (f32 VALU)
//  g2   : F2.Vn = s2 * F1.Vn @ Wq^T    (f32 VALU)
//  g3   : out   = scale*(Wv @ F2.Vc + bv) + x

typedef __attribute__((ext_vector_type(4))) float f32x4;
typedef __attribute__((ext_vector_type(2))) float f32x2;
typedef __attribute__((ext_vector_type(8))) short s16x8;

#define SCALE_S  0.08838834764831845f   // 1/sqrt(128)
#define SCALE_2S 0.17677669529663689f   // 2/sqrt(128)

__device__ __forceinline__ ushort f2bf(float f){
  uint u = __float_as_uint(f);
  u += 0x7fffu + ((u >> 16) & 1u);      // RTNE
  return (ushort)(u >> 16);
}

__global__ __launch_bounds__(256) void prep_kernel(const float* __restrict__ Wq, const float* __restrict__ Wv,
                                                   const float* __restrict__ gamma,
                                                   float* __restrict__ WqT, float* __restrict__ WvT,
                                                   float* __restrict__ scale){
  __shared__ float red[256];
  int t = threadIdx.x;
  float sq = 0.f, sv = 0.f;
  for (int i = t*4; i < 16384; i += 1024){
    f32x4 a = *(const f32x4*)(Wq + i);
    f32x4 bm = *(const f32x4*)(Wv + i);
    int o = i >> 7, k = i & 127;
    #pragma unroll
    for (int e=0; e<4; e++){
      sq += a[e]*a[e]; sv += bm[e]*bm[e];
      WqT[(k+e)*128 + o] = a[e];
      WvT[(k+e)*128 + o] = bm[e];
    }
  }
  red[t] = sq; __syncthreads();
  for (int s = 128; s > 0; s >>= 1){ if (t < s) red[t] += red[t+s]; __syncthreads(); }
  sq = red[0]; __syncthreads();
  red[t] = sv; __syncthreads();
  for (int s = 128; s > 0; s >>= 1){ if (t < s) red[t] += red[t+s]; __syncthreads(); }
  sv = red[0];
  if (t == 0){
    const double PHI = 5.5957572195283385;                 // LambertW(4096/e)
    double A = sqrt(32.0) * (4.0*PHI + 1.0);               // sqrt(N/C)*(4*phi+1)
    float bound = (float)(A * sqrt((double)sq) * sqrt((double)sv));
    scale[0] = gamma[0] / bound;
  }
}

// Q-conv + nq. grid (256,4), block 256. lane-dim = c (coalesced WqT),
// 8 consecutive n per thread (uniform x reads).
__global__ __launch_bounds__(256) void k1a_qconv(const float* __restrict__ x, const float* __restrict__ WqT,
                                                 const float* __restrict__ bq,
                                                 ushort* __restrict__ Qb, float* __restrict__ biasg){
  __shared__ float nq_part[2][8][2];
  int b = blockIdx.y;
  int n0 = blockIdx.x * 16;
  int c  = threadIdx.x & 127;
  int ng = threadIdx.x >> 7;
  int lane = threadIdx.x & 63;
  int wave = threadIdx.x >> 6;
  const float* xb = x + (size_t)b*524288 + n0 + ng*8;
  float a[8];
  float bias0 = bq[c];
  #pragma unroll
  for (int u=0; u<8; u++) a[u] = bias0;
  for (int i=0; i<128; i++){
    float w = WqT[i*128 + c];
    const float* xr = xb + (size_t)i*4096;
    f32x4 x0 = *(const f32x4*)xr;
    f32x4 x1 = *(const f32x4*)(xr + 4);
    #pragma unroll
    for (int u=0; u<4; u++){
      a[u]   = fmaf(w, x0[u], a[u]);
      a[u+4] = fmaf(w, x1[u], a[u+4]);
    }
  }
  ushort* qb = Qb + (size_t)(b*4096 + n0 + ng*8)*128 + c;
  #pragma unroll
  for (int u=0; u<8; u++) qb[u*128] = f2bf(a[u]);
  #pragma unroll
  for (int u=0; u<8; u++){
    float v = a[u]*a[u];
    #pragma unroll
    for (int d=1; d<64; d<<=1) v += __shfl_xor(v, d, 64);
    if (lane == 0) nq_part[ng][u][wave & 1] = v;
  }
  __syncthreads();
  if (threadIdx.x < 16){
    int g = threadIdx.x >> 3, u = threadIdx.x & 7;
    biasg[b*4096 + n0 + g*8 + u] = SCALE_S * (nq_part[g][u][0] + nq_part[g][u][1]);
  }
}

// Vt[b][c][m] = bf16(x_flat[b][m*128+c]). grid (64,4), block 256.
__global__ __launch_bounds__(256) void k1b_vt(const float* __restrict__ x, ushort* __restrict__ Vt){
  __shared__ __align__(16) ushort t[128*72];
  int b = blockIdx.y; int m0 = blockIdx.x*64;
  const float* xb = x + (size_t)b*524288 + (size_t)m0*128;
  for (int u = threadIdx.x; u < 64*32; u += 256){
    int m = u >> 5, seg = u & 31;
    f32x4 v = *(const f32x4*)(xb + m*128 + seg*4);
    #pragma unroll
    for (int e=0; e<4; e++) t[(seg*4+e)*72 + m] = f2bf(v[e]);
  }
  __syncthreads();
  ushort* vtb = Vt + (size_t)b*524288 + m0;
  for (int u = threadIdx.x; u < 128*8; u += 256){
    int c = u >> 3, seg = u & 7;
    *(s16x8*)(vtb + (size_t)c*4096 + seg*8) = *(const s16x8*)&t[c*72 + seg*8];
  }
}

// Flash attention. 1-D grid 256 (XCD-swizzled), block 256 = 4 waves.
// Waves {0,1} = pair 0 (keys 0..2047), waves {2,3} = pair 1 (keys 2048..4095).
// Wave-in-pair owns 32 q-rows. End: flash-state merge across pairs via LDS.
// LDS map (dynamic, 90624 B):
//   Kl  [2][64*136] u16  @ 0       (34816 B)  pad 136 -> balanced banks
//   Vl  [2][128*72] u16  @ 34816   (36864 B)  pad 72  -> balanced banks
//   Pl  [4][32*72]  u16  @ 71680   (18432 B)
//   bias[2][64]     f32  @ 90112   (512 B)
//   merge aliases Kl: macc[2][32*128] f32 @0 (32768), ml[2][32] f32x2 @32768
__global__ __launch_bounds__(256, 1) void k2_flash(const ushort* __restrict__ Qb, const ushort* __restrict__ Vt,
                                                   const float* __restrict__ biasg, float* __restrict__ F0){
  extern __shared__ __align__(16) char smem[];
  ushort* Kl    = (ushort*)(smem);
  ushort* Vl    = (ushort*)(smem + 34816);
  ushort* Pl    = (ushort*)(smem + 71680);
  float*  biasl = (float*)(smem + 90112);
  float*  macc  = (float*)(smem);            // merge alias
  f32x2*  ml    = (f32x2*)(smem + 32768);    // merge alias

  // XCD swizzle: bid&7 = XCD slot; batch b -> XCDs {2b,2b+1} (L2-resident KV)
  int bid = blockIdx.x;
  int xs = bid & 7, jj = bid >> 3;
  int b  = xs >> 1;
  int q0 = ((xs & 1) * 32 + jj) * 64;

  int tid = threadIdx.x;
  int wave = tid >> 6, lane = tid & 63;
  int pair = wave >> 1, wavein = wave & 1;
  int l15 = lane & 15, l4 = lane >> 4;
  const ushort* Qbb = Qb + (size_t)b*524288;
  const ushort* Vtb = Vt + (size_t)b*524288;
  const float*  bb  = biasg + (size_t)b*4096;
  int qw = q0 + wavein*32;
  int tp = tid >> 7;        // staging pair id
  int tt = tid & 127;

  s16x8 qf[2][4];           // Q frags in regs for the whole sweep
  #pragma unroll
  for (int qt=0; qt<2; qt++)
    #pragma unroll
    for (int ks=0; ks<4; ks++)
      qf[qt][ks] = *(const s16x8*)(Qbb + (size_t)(qw + qt*16 + l15)*128 + ks*32 + l4*8);

  f32x4 acc[2][8];
  #pragma unroll
  for (int qt=0; qt<2; qt++)
    #pragma unroll
    for (int ct=0; ct<8; ct++) acc[qt][ct] = (f32x4){0.f,0.f,0.f,0.f};
  float mrun[2][4], lrun[2][4];
  #pragma unroll
  for (int qt=0; qt<2; qt++)
    #pragma unroll
    for (int r=0; r<4; r++){ mrun[qt][r] = -1e30f; lrun[qt][r] = 0.f; }

  const ushort* Klp = Kl + pair*8704;
  const ushort* Vlp = Vl + pair*9216;
  ushort* Plw = Pl + wave*2304;

  for (int kt=0; kt<32; kt++){
    int m0s = tp*2048 + kt*64;          // this thread's STAGING tile base
    __syncthreads();
    #pragma unroll
    for (int p=0; p<8; p++){
      int u = tt + p*128;
      int r = u >> 4, seg = u & 15;
      *(s16x8*)&Kl[tp*8704 + r*136 + seg*8] = *(const s16x8*)(Qbb + (size_t)(m0s + r)*128 + seg*8);
    }
    #pragma unroll
    for (int p=0; p<8; p++){
      int u = tt + p*128;
      int cc = u >> 3, seg = u & 7;
      *(s16x8*)&Vl[tp*9216 + cc*72 + seg*8] = *(const s16x8*)(Vtb + (size_t)cc*4096 + m0s + seg*8);
    }
    if (tt < 64) biasl[tp*64 + tt] = bb[m0s + tt];
    __syncthreads();

    float bv_[4];
    #pragma unroll
    for (int mt=0; mt<4; mt++) bv_[mt] = biasl[pair*64 + mt*16 + l15];

    f32x4 sa[2][4];
    #pragma unroll
    for (int qt=0; qt<2; qt++)
      #pragma unroll
      for (int mt=0; mt<4; mt++) sa[qt][mt] = (f32x4){0.f,0.f,0.f,0.f};
    #pragma unroll
    for (int ks=0; ks<4; ks++){
      s16x8 kb[4];
      #pragma unroll
      for (int mt=0; mt<4; mt++)
        kb[mt] = *(const s16x8*)&Klp[(mt*16 + l15)*136 + ks*32 + l4*8];
      #pragma unroll
      for (int qt=0; qt<2; qt++)
        #pragma unroll
        for (int mt=0; mt<4; mt++)
          sa[qt][mt] = __builtin_amdgcn_mfma_f32_16x16x32_bf16(qf[qt][ks], kb[mt], sa[qt][mt], 0, 0, 0);
    }
    // online softmax (rows = 4*l4+r per qt; cols spread over l15 x mt)
    #pragma unroll
    for (int qt=0; qt<2; qt++){
      #pragma unroll
      for (int mt=0; mt<4; mt++)
        #pragma unroll
        for (int r=0; r<4; r++)
          sa[qt][mt][r] = fmaf(SCALE_2S, sa[qt][mt][r], -bv_[mt]);
      float mx[4];
      #pragma unroll
      for (int r=0; r<4; r++)
        mx[r] = fmaxf(fmaxf(sa[qt][0][r], sa[qt][1][r]), fmaxf(sa[qt][2][r], sa[qt][3][r]));
      #pragma unroll
      for (int d=1; d<16; d<<=1)
        #pragma unroll
        for (int r=0; r<4; r++)
          mx[r] = fmaxf(mx[r], __shfl_xor(mx[r], d, 64));
      float corr[4];
      #pragma unroll
      for (int r=0; r<4; r++){
        float mn = fmaxf(mrun[qt][r], mx[r]);
        corr[r] = __expf(mrun[qt][r] - mn);
        mrun[qt][r] = mn;
      }
      float rs[4];
      #pragma unroll
      for (int r=0; r<4; r++) rs[r] = 0.f;
      #pragma unroll
      for (int mt=0; mt<4; mt++)
        #pragma unroll
        for (int r=0; r<4; r++){
          float p = __expf(sa[qt][mt][r] - mrun[qt][r]);
          sa[qt][mt][r] = p;
          rs[r] += p;
        }
      #pragma unroll
      for (int d=1; d<16; d<<=1)
        #pragma unroll
        for (int r=0; r<4; r++)
          rs[r] += __shfl_xor(rs[r], d, 64);
      #pragma unroll
      for (int r=0; r<4; r++) lrun[qt][r] = lrun[qt][r]*corr[r] + rs[r];
      #pragma unroll
      for (int ct=0; ct<8; ct++)
        #pragma unroll
        for (int r=0; r<4; r++) acc[qt][ct][r] *= corr[r];
      #pragma unroll
      for (int mt=0; mt<4; mt++)
        #pragma unroll
        for (int r=0; r<4; r++)
          Plw[(qt*16 + l4*4 + r)*72 + mt*16 + l15] = f2bf(sa[qt][mt][r]);
    }
    // PV (V-frags shared across both qt)
    #pragma unroll
    for (int ks2=0; ks2<2; ks2++){
      s16x8 pa0 = *(const s16x8*)&Plw[(l15)*72 + ks2*32 + l4*8];
      s16x8 pa1 = *(const s16x8*)&Plw[(16 + l15)*72 + ks2*32 + l4*8];
      #pragma unroll
      for (int ct=0; ct<8; ct++){
        s16x8 vb = *(const s16x8*)&Vlp[(ct*16 + l15)*72 + ks2*32 + l4*8];
        acc[0][ct] = __builtin_amdgcn_mfma_f32_16x16x32_bf16(pa0, vb, acc[0][ct], 0, 0, 0);
        acc[1][ct] = __builtin_amdgcn_mfma_f32_16x16x32_bf16(pa1, vb, acc[1][ct], 0, 0, 0);
      }
    }
  }

  // ---- merge key-split pairs ----
  __syncthreads();
  if (pair == 1){
    #pragma unroll
    for (int qt=0; qt<2; qt++)
      #pragma unroll
      for (int ct=0; ct<8; ct++)
        #pragma unroll
        for (int r=0; r<4; r++)
          macc[wavein*4096 + (qt*16 + l4*4 + r)*128 + ct*16 + l15] = acc[qt][ct][r];
    if (l15 == 0){
      #pragma unroll
      for (int qt=0; qt<2; qt++)
        #pragma unroll
        for (int r=0; r<4; r++)
          ml[wavein*32 + qt*16 + l4*4 + r] = (f32x2){mrun[qt][r], lrun[qt][r]};
    }
  }
  __syncthreads();
  if (pair == 0){
    float* F0b = F0 + (size_t)b*524288;
    #pragma unroll
    for (int qt=0; qt<2; qt++){
      float aA[4], aB[4], inv[4];
      #pragma unroll
      for (int r=0; r<4; r++){
        int row = qt*16 + l4*4 + r;
        f32x2 mb = ml[wavein*32 + row];
        float ms = fmaxf(mrun[qt][r], mb.x);
        aA[r] = __expf(mrun[qt][r] - ms);
        aB[r] = __expf(mb.x - ms);
        inv[r] = 1.0f / (aA[r]*lrun[qt][r] + aB[r]*mb.y);
      }
      #pragma unroll
      for (int ct=0; ct<8; ct++)
        #pragma unroll
        for (int r=0; r<4; r++){
          int row = qt*16 + l4*4 + r;
          float ob = macc[wavein*4096 + row*128 + ct*16 + l15];
          F0b[(size_t)(qw + row)*128 + ct*16 + l15] = (aA[r]*acc[qt][ct][r] + aB[r]*ob) * inv[r];
        }
    }
  }
}

// out.Vc[o][j] = bias[o] + sum_i W[o][i]*M.Vc[i][j]
__global__ __launch_bounds__(256) void g_mid(const float* __restrict__ M, const float* __restrict__ WT,
                                             const float* __restrict__ bias, float* __restrict__ out){
  int b = blockIdx.y;
  int j0 = blockIdx.x * 16;
  int o  = threadIdx.x & 127;
  int jg = threadIdx.x >> 7;
  const float* Mb = M + (size_t)b*524288 + j0 + jg*8;
  float a[8];
  float bo = bias[o];
  #pragma unroll
  for (int u=0; u<8; u++) a[u] = bo;
  for (int i=0; i<128; i++){
    float w = WT[i*128 + o];
    const float* mr = Mb + (size_t)i*4096;
    f32x4 m0 = *(const f32x4*)mr;
    f32x4 m1 = *(const f32x4*)(mr + 4);
    #pragma unroll
    for (int u=0; u<4; u++){
      a[u]   = fmaf(w, m0[u], a[u]);
      a[u+4] = fmaf(w, m1[u], a[u+4]);
    }
  }
  float* ob = out + (size_t)b*524288 + (size_t)o*4096 + j0 + jg*8;
  #pragma unroll
  for (int u=0; u<8; u++) ob[u] = a[u];
}

// F2.Vn[n][p] = s2 * sum_k F1.Vn[n][k] * Wq[p][k]
__global__ __launch_bounds__(256) void g2_bmm(const float* __restrict__ F1, const float* __restrict__ WqT,
                                              float* __restrict__ F2){
  int b = blockIdx.y;
  int n0 = blockIdx.x * 16;
  int p  = threadIdx.x & 127;
  int ng = threadIdx.x >> 7;
  const float* Fb = F1 + (size_t)b*524288 + (size_t)(n0 + ng*8)*128;
  float a[8] = {0.f,0.f,0.f,0.f,0.f,0.f,0.f,0.f};
  for (int k=0; k<128; k++){
    float w = WqT[k*128 + p];
    #pragma unroll
    for (int u=0; u<8; u++) a[u] = fmaf(w, Fb[u*128 + k], a[u]);
  }
  float* ob = F2 + (size_t)b*524288 + (size_t)(n0 + ng*8)*128 + p;
  #pragma unroll
  for (int u=0; u<8; u++) ob[u*128] = a[u] * SCALE_S;
}

// out = scale*(Wv @ M.Vc + bv) + x
__global__ __launch_bounds__(256) void g_final(const float* __restrict__ M, const float* __restrict__ WT,
                                               const float* __restrict__ bias, const float* __restrict__ x,
                                               const float* __restrict__ scale, float* __restrict__ out){
  int b = blockIdx.y;
  int j0 = blockIdx.x * 16;
  int o  = threadIdx.x & 127;
  int jg = threadIdx.x >> 7;
  const float* Mb = M + (size_t)b*524288 + j0 + jg*8;
  float a[8];
  float bo = bias[o];
  #pragma unroll
  for (int u=0; u<8; u++) a[u] = bo;
  for (int i=0; i<128; i++){
    float w = WT[i*128 + o];
    const float* mr = Mb + (size_t)i*4096;
    f32x4 m0 = *(const f32x4*)mr;
    f32x4 m1 = *(const f32x4*)(mr + 4);
    #pragma unroll
    for (int u=0; u<4; u++){
      a[u]   = fmaf(w, m0[u], a[u]);
      a[u+4] = fmaf(w, m1[u], a[u+4]);
    }
  }
  float sc = scale[0];
  const float* xr = x + (size_t)b*524288 + (size_t)o*4096 + j0 + jg*8;
  float* ob = out + (size_t)b*524288 + (size_t)o*4096 + j0 + jg*8;
  #pragma unroll
  for (int u=0; u<8; u++) ob[u] = fmaf(sc, a[u], xr[u]);
}

extern "C" void kernel_launch(void* const* d_in, const int* in_sizes, int n_in,
                              void* d_out, int out_size, void* d_ws, size_t ws_size,
                              hipStream_t stream){
  const float* x     = (const float*)d_in[0];
  const float* Wq    = (const float*)d_in[1];
  const float* bq    = (const float*)d_in[2];
  const float* Wv    = (const float*)d_in[3];
  const float* bv    = (const float*)d_in[4];
  const float* gamma = (const float*)d_in[5];
  char* ws = (char*)d_ws;
  // layout (~16.2 MB): [Qb 4MB | Vt 4MB] (reused as F1 8MB) | biasg | WqT | WvT | scale | F0/F2 8MB
  ushort* Qb    = (ushort*)(ws + 0);
  ushort* Vt    = (ushort*)(ws + 4194304);
  float*  F1    = (float*)(ws + 0);          // alias: written after Qb/Vt dead
  float*  biasg = (float*)(ws + 8388608);
  float*  WqT   = (float*)(ws + 8454144);
  float*  WvT   = (float*)(ws + 8519680);
  float*  scale = (float*)(ws + 8585216);
  float*  F0    = (float*)(ws + 8585280);
  float*  F2    = F0;                        // alias: G2 writes after G1 read F0
  float*  out   = (float*)d_out;

  prep_kernel<<<1, 256, 0, stream>>>(Wq, Wv, gamma, WqT, WvT, scale);
  k1a_qconv <<<dim3(256,4), 256, 0, stream>>>(x, WqT, bq, Qb, biasg);
  k1b_vt    <<<dim3(64,4),  256, 0, stream>>>(x, Vt);
  k2_flash  <<<256, 256, 90624, stream>>>(Qb, Vt, biasg, F0);
  g_mid     <<<dim3(256,4), 256, 0, stream>>>(F0, WqT, bq, F1);
  g2_bmm    <<<dim3(256,4), 256, 0, stream>>>(F1, WqT, F2);
  g_final   <<<dim3(256,4), 256, 0, stream>>>(F2, WvT, bv, x, scale, out);
}

// Round 5
// 364.142 us; speedup vs baseline: 1.3667x; 1.3667x over previous
//
#include <hip/hip_runtime.h>

// L2_Self_Attn flattened pipeline for MI355X (gfx950).
// B=4, C=128, H=W=64, N=4096. All reshapes are flat-view reinterpretations.
// Attention branch is suppressed by gamma/bound ~6e-6 -> bf16 MFMA is safe.
//
// k2 design: no K/V LDS staging (L2-resident, m169 lesson), 4-way key
// split (512 blocks, 2/CU, 8 waves/CU), swapped QK^T (D[key][query] ->
// softmax mostly in-register, 2 shfl rounds), packed P via XOR-swizzled
// per-wave LDS buffer, exact skip-rescale, 3-step tree merge at end.

typedef __attribute__((ext_vector_type(4))) float f32x4;
typedef __attribute__((ext_vector_type(2))) float f32x2;
typedef __attribute__((ext_vector_type(8))) short s16x8;

#define SCALE_S  0.08838834764831845f   // 1/sqrt(128)
#define SCALE_2S 0.17677669529663689f   // 2/sqrt(128)

__device__ __forceinline__ ushort f2bf(float f){
  uint u = __float_as_uint(f);
  u += 0x7fffu + ((u >> 16) & 1u);      // RTNE
  return (ushort)(u >> 16);
}
__device__ __forceinline__ uint packbf(float lo, float hi){
  return (uint)f2bf(lo) | ((uint)f2bf(hi) << 16);
}

// grid(2): block 0 = Wq->WqT + scale, block 1 = Wv->WvT. LDS-tiled transpose.
__global__ __launch_bounds__(256) void prep_kernel(const float* __restrict__ Wq, const float* __restrict__ Wv,
                                                   const float* __restrict__ gamma,
                                                   float* __restrict__ WqT, float* __restrict__ WvT,
                                                   float* __restrict__ scale){
  __shared__ float tile[32][33];
  __shared__ float red[256];
  int m = blockIdx.x;
  const float* S = m ? Wv : Wq;
  float* D = m ? WvT : WqT;
  int t = threadIdx.x;
  if (m == 0){
    float sq = 0.f, sv = 0.f;
    for (int i = t*4; i < 16384; i += 1024){
      f32x4 a = *(const f32x4*)(Wq + i);
      f32x4 b = *(const f32x4*)(Wv + i);
      #pragma unroll
      for (int e=0; e<4; e++){ sq += a[e]*a[e]; sv += b[e]*b[e]; }
    }
    red[t] = sq; __syncthreads();
    for (int s = 128; s > 0; s >>= 1){ if (t < s) red[t] += red[t+s]; __syncthreads(); }
    sq = red[0]; __syncthreads();
    red[t] = sv; __syncthreads();
    for (int s = 128; s > 0; s >>= 1){ if (t < s) red[t] += red[t+s]; __syncthreads(); }
    sv = red[0];
    if (t == 0){
      const double PHI = 5.5957572195283385;                 // LambertW(4096/e)
      double A = sqrt(32.0) * (4.0*PHI + 1.0);               // sqrt(N/C)*(4*phi+1)
      float bound = (float)(A * sqrt((double)sq) * sqrt((double)sv));
      scale[0] = gamma[0] / bound;
    }
  }
  int r = t >> 3, cq = (t & 7) * 4;
  for (int tt = 0; tt < 16; tt++){
    int tr = tt >> 2, tc = tt & 3;
    __syncthreads();
    f32x4 v = *(const f32x4*)(S + (tr*32 + r)*128 + tc*32 + cq);
    #pragma unroll
    for (int e=0; e<4; e++) tile[r][cq+e] = v[e];
    __syncthreads();
    f32x4 o;
    #pragma unroll
    for (int e=0; e<4; e++) o[e] = tile[cq+e][r];
    *(f32x4*)(D + (tc*32 + r)*128 + tr*32 + cq) = o;
  }
}

// Q-conv + nq. grid (256,4), block 256. lane-dim = c (coalesced WqT),
// 8 consecutive n per thread (uniform x reads).
__global__ __launch_bounds__(256) void k1a_qconv(const float* __restrict__ x, const float* __restrict__ WqT,
                                                 const float* __restrict__ bq,
                                                 ushort* __restrict__ Qb, float* __restrict__ biasg){
  __shared__ float nq_part[2][8][2];
  int b = blockIdx.y;
  int n0 = blockIdx.x * 16;
  int c  = threadIdx.x & 127;
  int ng = threadIdx.x >> 7;
  int lane = threadIdx.x & 63;
  int wave = threadIdx.x >> 6;
  const float* xb = x + (size_t)b*524288 + n0 + ng*8;
  float a[8];
  float bias0 = bq[c];
  #pragma unroll
  for (int u=0; u<8; u++) a[u] = bias0;
  for (int i=0; i<128; i++){
    float w = WqT[i*128 + c];
    const float* xr = xb + (size_t)i*4096;
    f32x4 x0 = *(const f32x4*)xr;
    f32x4 x1 = *(const f32x4*)(xr + 4);
    #pragma unroll
    for (int u=0; u<4; u++){
      a[u]   = fmaf(w, x0[u], a[u]);
      a[u+4] = fmaf(w, x1[u], a[u+4]);
    }
  }
  ushort* qb = Qb + (size_t)(b*4096 + n0 + ng*8)*128 + c;
  #pragma unroll
  for (int u=0; u<8; u++) qb[u*128] = f2bf(a[u]);
  #pragma unroll
  for (int u=0; u<8; u++){
    float v = a[u]*a[u];
    #pragma unroll
    for (int d=1; d<64; d<<=1) v += __shfl_xor(v, d, 64);
    if (lane == 0) nq_part[ng][u][wave & 1] = v;
  }
  __syncthreads();
  if (threadIdx.x < 16){
    int g = threadIdx.x >> 3, u = threadIdx.x & 7;
    biasg[b*4096 + n0 + g*8 + u] = SCALE_S * (nq_part[g][u][0] + nq_part[g][u][1]);
  }
}

// Vt[b][c][m] = bf16(x_flat[b][m*128+c]). grid (64,4), block 256.
__global__ __launch_bounds__(256) void k1b_vt(const float* __restrict__ x, ushort* __restrict__ Vt){
  __shared__ __align__(16) ushort t[128*72];
  int b = blockIdx.y; int m0 = blockIdx.x*64;
  const float* xb = x + (size_t)b*524288 + (size_t)m0*128;
  for (int u = threadIdx.x; u < 64*32; u += 256){
    int m = u >> 5, seg = u & 31;
    f32x4 v = *(const f32x4*)(xb + m*128 + seg*4);
    #pragma unroll
    for (int e=0; e<4; e++) t[(seg*4+e)*72 + m] = f2bf(v[e]);
  }
  __syncthreads();
  ushort* vtb = Vt + (size_t)b*524288 + m0;
  for (int u = threadIdx.x; u < 128*8; u += 256){
    int c = u >> 3, seg = u & 7;
    *(s16x8*)(vtb + (size_t)c*4096 + seg*8) = *(const s16x8*)&t[c*72 + seg*8];
  }
}

// Flash attention, no-staging. 1-D grid 512 (XCD-swizzled), block 256 = 4 waves.
// All 4 waves: SAME 32 q-rows, 4-way key split (wave w: keys [w*1024,(w+1)*1024)).
// Swapped QK^T: sa = mfma(K,Q) -> D[key=mt*16+l4*4+r][query=l15].
// P relayout: packed b64 writes into per-wave LDS buffer, 128B rows,
// XOR swizzle byte ^= (row&7)<<4 (bank-balanced, verified bijective).
// End: tree merge of 4 flash states via LDS (aliases P region after barrier).
// LDS 33280 B: macc/P [0,32768), ml @32768 (512 B). 2 blocks/CU.
__global__ __launch_bounds__(256, 2) void k2_flash(const ushort* __restrict__ Qb, const ushort* __restrict__ Vt,
                                                   const float* __restrict__ biasg, float* __restrict__ F0){
  extern __shared__ __align__(16) char smem[];
  int bid = blockIdx.x;
  int xs = bid & 7, jj = bid >> 3;
  int b  = xs >> 1;                       // batch -> XCD pair (L2-resident K/V)
  int q0 = ((xs & 1) * 64 + jj) * 32;     // 128 q-tiles per batch

  int tid = threadIdx.x;
  int wave = tid >> 6, lane = tid & 63;
  int l15 = lane & 15, l4 = lane >> 4;
  const ushort* Qbb = Qb + (size_t)b*524288;
  const ushort* Vtb = Vt + (size_t)b*524288;
  const float*  bb  = biasg + (size_t)b*4096;
  char* Pb = smem + wave*4096;            // per-wave P buffer: 32 rows x 128B

  s16x8 qf[2][4];                         // Q frags (B-operand) for whole sweep
  #pragma unroll
  for (int qt=0; qt<2; qt++)
    #pragma unroll
    for (int ks=0; ks<4; ks++)
      qf[qt][ks] = *(const s16x8*)(Qbb + (size_t)(q0 + qt*16 + l15)*128 + ks*32 + l4*8);

  f32x4 acc[2][8];
  #pragma unroll
  for (int qt=0; qt<2; qt++)
    #pragma unroll
    for (int ct=0; ct<8; ct++) acc[qt][ct] = (f32x4){0.f,0.f,0.f,0.f};
  float mrun[2] = {-1e30f, -1e30f};       // per lane: state of query l15 (per qt)
  float lrun[2] = {0.f, 0.f};

  for (int kt=0; kt<16; kt++){
    int m0 = wave*1024 + kt*64;
    f32x4 bv[4];
    #pragma unroll
    for (int mt=0; mt<4; mt++)
      bv[mt] = *(const f32x4*)(bb + m0 + mt*16 + l4*4);

    f32x4 sa[2][4];
    #pragma unroll
    for (int qt=0; qt<2; qt++)
      #pragma unroll
      for (int mt=0; mt<4; mt++) sa[qt][mt] = (f32x4){0.f,0.f,0.f,0.f};
    #pragma unroll
    for (int ks=0; ks<4; ks++){
      s16x8 kb[4];                        // A-operand: K rows = key rows of Qb
      #pragma unroll
      for (int mt=0; mt<4; mt++)
        kb[mt] = *(const s16x8*)(Qbb + (size_t)(m0 + mt*16 + l15)*128 + ks*32 + l4*8);
      #pragma unroll
      for (int qt=0; qt<2; qt++)
        #pragma unroll
        for (int mt=0; mt<4; mt++)
          sa[qt][mt] = __builtin_amdgcn_mfma_f32_16x16x32_bf16(kb[mt], qf[qt][ks], sa[qt][mt], 0, 0, 0);
    }
    // softmax: lane holds 16 key-scores for its query (l15), per qt
    #pragma unroll
    for (int qt=0; qt<2; qt++){
      #pragma unroll
      for (int mt=0; mt<4; mt++)
        #pragma unroll
        for (int r=0; r<4; r++)
          sa[qt][mt][r] = fmaf(SCALE_2S, sa[qt][mt][r], -bv[mt][r]);
      float m16 = sa[qt][0][0];
      #pragma unroll
      for (int mt=0; mt<4; mt++)
        #pragma unroll
        for (int r=0; r<4; r++) m16 = fmaxf(m16, sa[qt][mt][r]);
      m16 = fmaxf(m16, __shfl_xor(m16, 16, 64));
      m16 = fmaxf(m16, __shfl_xor(m16, 32, 64));
      int need = __any(m16 > mrun[qt]);
      float mn = fmaxf(mrun[qt], m16);
      float corr = 1.0f;
      if (need){ corr = __expf(mrun[qt] - mn); mrun[qt] = mn; }
      float rs = 0.f;
      #pragma unroll
      for (int mt=0; mt<4; mt++)
        #pragma unroll
        for (int r=0; r<4; r++){
          float p = __expf(sa[qt][mt][r] - mn);
          sa[qt][mt][r] = p;
          rs += p;
        }
      rs += __shfl_xor(rs, 16, 64);
      rs += __shfl_xor(rs, 32, 64);
      lrun[qt] = lrun[qt]*corr + rs;
      if (need){
        float cA[4];
        #pragma unroll
        for (int r=0; r<4; r++) cA[r] = __shfl(corr, l4*4 + r, 64);  // acc rows = queries l4*4+r
        #pragma unroll
        for (int ct=0; ct<8; ct++)
          #pragma unroll
          for (int r=0; r<4; r++) acc[qt][ct][r] *= cA[r];
      }
      int row = qt*16 + l15;
      int sw = (row & 7) << 4;
      #pragma unroll
      for (int mt=0; mt<4; mt++){
        uint2 w2;
        w2.x = packbf(sa[qt][mt][0], sa[qt][mt][1]);
        w2.y = packbf(sa[qt][mt][2], sa[qt][mt][3]);
        *(uint2*)(Pb + ((row*128 + mt*32 + l4*8) ^ sw)) = w2;
      }
    }
    // PV: pa from P-LDS (A-operand, rows=queries), vb direct from Vt (L2)
    int row0 = l15, row1 = 16 + l15;
    int sw0 = (row0 & 7) << 4;            // row0&7 == row1&7
    #pragma unroll
    for (int ks2=0; ks2<2; ks2++){
      s16x8 pa0 = *(const s16x8*)(Pb + ((row0*128 + ks2*64 + l4*16) ^ sw0));
      s16x8 pa1 = *(const s16x8*)(Pb + ((row1*128 + ks2*64 + l4*16) ^ sw0));
      #pragma unroll
      for (int ct=0; ct<8; ct++){
        s16x8 vb = *(const s16x8*)(Vtb + (size_t)(ct*16 + l15)*4096 + m0 + ks2*32 + l4*8);
        acc[0][ct] = __builtin_amdgcn_mfma_f32_16x16x32_bf16(pa0, vb, acc[0][ct], 0, 0, 0);
        acc[1][ct] = __builtin_amdgcn_mfma_f32_16x16x32_bf16(pa1, vb, acc[1][ct], 0, 0, 0);
      }
    }
  }

  // ---- tree merge of 4 key-split states ----
  float* macc = (float*)smem;             // [2][32][128] (aliases P bufs)
  f32x2* ml   = (f32x2*)(smem + 32768);   // [2][32]
  __syncthreads();
  if (wave >= 2){
    int wi = wave - 2;
    #pragma unroll
    for (int qt=0; qt<2; qt++){
      #pragma unroll
      for (int ct=0; ct<8; ct++)
        #pragma unroll
        for (int r=0; r<4; r++)
          macc[wi*4096 + (qt*16 + l4*4 + r)*128 + ct*16 + l15] = acc[qt][ct][r];
      if (lane < 16) ml[wi*32 + qt*16 + lane] = (f32x2){mrun[qt], lrun[qt]};
    }
  }
  __syncthreads();
  float mA[2][4], lA[2][4];
  if (wave < 2){
    int wi = wave;
    #pragma unroll
    for (int qt=0; qt<2; qt++){
      #pragma unroll
      for (int r=0; r<4; r++){
        mA[qt][r] = __shfl(mrun[qt], l4*4 + r, 64);   // own state -> acc rows
        lA[qt][r] = __shfl(lrun[qt], l4*4 + r, 64);
        f32x2 pm = ml[wi*32 + qt*16 + l4*4 + r];
        float ms = fmaxf(mA[qt][r], pm.x);
        float aA = __expf(mA[qt][r] - ms);
        float aB = __expf(pm.x - ms);
        lA[qt][r] = aA*lA[qt][r] + aB*pm.y;
        mA[qt][r] = ms;
        #pragma unroll
        for (int ct=0; ct<8; ct++)
          acc[qt][ct][r] = aA*acc[qt][ct][r] + aB*macc[wi*4096 + (qt*16 + l4*4 + r)*128 + ct*16 + l15];
      }
    }
  }
  __syncthreads();
  if (wave == 1){
    #pragma unroll
    for (int qt=0; qt<2; qt++){
      #pragma unroll
      for (int ct=0; ct<8; ct++)
        #pragma unroll
        for (int r=0; r<4; r++)
          macc[(qt*16 + l4*4 + r)*128 + ct*16 + l15] = acc[qt][ct][r];
      if (l15 == 0){
        #pragma unroll
        for (int r=0; r<4; r++)
          ml[qt*16 + l4*4 + r] = (f32x2){mA[qt][r], lA[qt][r]};
      }
    }
  }
  __syncthreads();
  if (wave == 0){
    float* F0b = F0 + (size_t)b*524288;
    #pragma unroll
    for (int qt=0; qt<2; qt++){
      #pragma unroll
      for (int r=0; r<4; r++){
        f32x2 pm = ml[qt*16 + l4*4 + r];
        float ms = fmaxf(mA[qt][r], pm.x);
        float aA = __expf(mA[qt][r] - ms);
        float aB = __expf(pm.x - ms);
        float inv = 1.0f / (aA*lA[qt][r] + aB*pm.y);
        #pragma unroll
        for (int ct=0; ct<8; ct++){
          float ob = macc[(qt*16 + l4*4 + r)*128 + ct*16 + l15];
          F0b[(size_t)(q0 + qt*16 + l4*4 + r)*128 + ct*16 + l15] = (aA*acc[qt][ct][r] + aB*ob) * inv;
        }
      }
    }
  }
}

// out.Vc[o][j] = bias[o] + sum_i W[o][i]*M.Vc[i][j]
__global__ __launch_bounds__(256) void g_mid(const float* __restrict__ M, const float* __restrict__ WT,
                                             const float* __restrict__ bias, float* __restrict__ out){
  int b = blockIdx.y;
  int j0 = blockIdx.x * 16;
  int o  = threadIdx.x & 127;
  int jg = threadIdx.x >> 7;
  const float* Mb = M + (size_t)b*524288 + j0 + jg*8;
  float a[8];
  float bo = bias[o];
  #pragma unroll
  for (int u=0; u<8; u++) a[u] = bo;
  for (int i=0; i<128; i++){
    float w = WT[i*128 + o];
    const float* mr = Mb + (size_t)i*4096;
    f32x4 m0 = *(const f32x4*)mr;
    f32x4 m1 = *(const f32x4*)(mr + 4);
    #pragma unroll
    for (int u=0; u<4; u++){
      a[u]   = fmaf(w, m0[u], a[u]);
      a[u+4] = fmaf(w, m1[u], a[u+4]);
    }
  }
  float* ob = out + (size_t)b*524288 + (size_t)o*4096 + j0 + jg*8;
  #pragma unroll
  for (int u=0; u<8; u++) ob[u] = a[u];
}

// F2.Vn[n][p] = s2 * sum_k F1.Vn[n][k] * Wq[p][k]
__global__ __launch_bounds__(256) void g2_bmm(const float* __restrict__ F1, const float* __restrict__ WqT,
                                              float* __restrict__ F2){
  int b = blockIdx.y;
  int n0 = blockIdx.x * 16;
  int p  = threadIdx.x & 127;
  int ng = threadIdx.x >> 7;
  const float* Fb = F1 + (size_t)b*524288 + (size_t)(n0 + ng*8)*128;
  float a[8] = {0.f,0.f,0.f,0.f,0.f,0.f,0.f,0.f};
  for (int k=0; k<128; k++){
    float w = WqT[k*128 + p];
    #pragma unroll
    for (int u=0; u<8; u++) a[u] = fmaf(w, Fb[u*128 + k], a[u]);
  }
  float* ob = F2 + (size_t)b*524288 + (size_t)(n0 + ng*8)*128 + p;
  #pragma unroll
  for (int u=0; u<8; u++) ob[u*128] = a[u] * SCALE_S;
}

// out = scale*(Wv @ M.Vc + bv) + x
__global__ __launch_bounds__(256) void g_final(const float* __restrict__ M, const float* __restrict__ WT,
                                               const float* __restrict__ bias, const float* __restrict__ x,
                                               const float* __restrict__ scale, float* __restrict__ out){
  int b = blockIdx.y;
  int j0 = blockIdx.x * 16;
  int o  = threadIdx.x & 127;
  int jg = threadIdx.x >> 7;
  const float* Mb = M + (size_t)b*524288 + j0 + jg*8;
  float a[8];
  float bo = bias[o];
  #pragma unroll
  for (int u=0; u<8; u++) a[u] = bo;
  for (int i=0; i<128; i++){
    float w = WT[i*128 + o];
    const float* mr = Mb + (size_t)i*4096;
    f32x4 m0 = *(const f32x4*)mr;
    f32x4 m1 = *(const f32x4*)(mr + 4);
    #pragma unroll
    for (int u=0; u<4; u++){
      a[u]   = fmaf(w, m0[u], a[u]);
      a[u+4] = fmaf(w, m1[u], a[u+4]);
    }
  }
  float sc = scale[0];
  const float* xr = x + (size_t)b*524288 + (size_t)o*4096 + j0 + jg*8;
  float* ob = out + (size_t)b*524288 + (size_t)o*4096 + j0 + jg*8;
  #pragma unroll
  for (int u=0; u<8; u++) ob[u] = fmaf(sc, a[u], xr[u]);
}

extern "C" void kernel_launch(void* const* d_in, const int* in_sizes, int n_in,
                              void* d_out, int out_size, void* d_ws, size_t ws_size,
                              hipStream_t stream){
  const float* x     = (const float*)d_in[0];
  const float* Wq    = (const float*)d_in[1];
  const float* bq    = (const float*)d_in[2];
  const float* Wv    = (const float*)d_in[3];
  const float* bv    = (const float*)d_in[4];
  const float* gamma = (const float*)d_in[5];
  char* ws = (char*)d_ws;
  // layout (~16.2 MB): [Qb 4MB | Vt 4MB] (reused as F1 8MB) | biasg | WqT | WvT | scale | F0/F2 8MB
  ushort* Qb    = (ushort*)(ws + 0);
  ushort* Vt    = (ushort*)(ws + 4194304);
  float*  F1    = (float*)(ws + 0);          // alias: written after Qb/Vt dead
  float*  biasg = (float*)(ws + 8388608);
  float*  WqT   = (float*)(ws + 8454144);
  float*  WvT   = (float*)(ws + 8519680);
  float*  scale = (float*)(ws + 8585216);
  float*  F0    = (float*)(ws + 8585280);
  float*  F2    = F0;                        // alias: G2 writes after G1 read F0
  float*  out   = (float*)d_out;

  prep_kernel<<<2, 256, 0, stream>>>(Wq, Wv, gamma, WqT, WvT, scale);
  k1a_qconv <<<dim3(256,4), 256, 0, stream>>>(x, WqT, bq, Qb, biasg);
  k1b_vt    <<<dim3(64,4),  256, 0, stream>>>(x, Vt);
  k2_flash  <<<512, 256, 33280, stream>>>(Qb, Vt, biasg, F0);
  g_mid     <<<dim3(256,4), 256, 0, stream>>>(F0, WqT, bq, F1);
  g2_bmm    <<<dim3(256,4), 256, 0, stream>>>(F1, WqT, F2);
  g_final   <<<dim3(256,4), 256, 0, stream>>>(F2, WvT, bv, x, scale, out);
}